// Round 15
// baseline (154.734 us; speedup 1.0000x reference)
//
#include <hip/hip_runtime.h>
#include <stdint.h>

typedef unsigned int u32;
typedef unsigned long long u64;
typedef int v4i  __attribute__((ext_vector_type(4)));
typedef int v16i __attribute__((ext_vector_type(16)));

#define K_MSG   1024
#define N_CODE  2048
#define NB      32768

// ------------- pack G -> fragment-major i8 B (proven round 10-14) -----------
__global__ void pack_gBF(const int* __restrict__ G, u32* __restrict__ bf) {
    int idx = blockIdx.x * blockDim.x + threadIdx.x;   // 524288
    const int j  = idx & (N_CODE - 1);                 // coalesced G reads
    const int kq = idx >> 11;                          // dword of k: 0..255
    u32 p = 0;
#pragma unroll
    for (int i = 0; i < 4; ++i) {
        int v = G[(size_t)(kq * 4 + i) * N_CODE + j];
        p |= (u32)(v & 1) << (8 * i);
    }
    const int jb = j >> 5, jr = j & 31;
    const int kb = kq >> 3, hi = (kq >> 2) & 1, b4 = kq & 3;
    bf[(size_t)(jb * 32 + kb) * 256 + hi * 128 + jr * 4 + b4] = p;
}

// ---------------- wave-specialized GEMM -------------------------------------
// 512 blocks x 512 thr (8 waves). Waves 0-3: k-loop (tile 64x64) + ballot->pk
// LDS (double-buffered). Waves 4-7: pure storers — expand pk of the PREVIOUS
// pass to coalesced dwordx4 stores. Separate waves => separate vmcnt FIFOs:
// B-load waits never drain output stores. 8 N-passes x 256 cols, 1 barrier/pass.

#define MFMA_I8(va, vb, vc) __builtin_amdgcn_mfma_i32_32x32x32_i8(va, vb, vc, 0, 0, 0)

#define MFMAS(sfx) do {                                 \
    acc[0][0] = MFMA_I8(a0##sfx, b0##sfx, acc[0][0]);   \
    acc[0][1] = MFMA_I8(a0##sfx, b1##sfx, acc[0][1]);   \
    acc[1][0] = MFMA_I8(a1##sfx, b0##sfx, acc[1][0]);   \
    acc[1][1] = MFMA_I8(a1##sfx, b1##sfx, acc[1][1]);   \
} while (0)

#define LOADS(sfx, s_) do {                                         \
    int ao_ = lr * 1024 + ((((s_) * 32) + hi * 16) ^ axor);         \
    a0##sfx = *(const v4i*)(As + ao_);                              \
    a1##sfx = *(const v4i*)(As + ao_ + 32768);                      \
    b0##sfx = *(const v4i*)(bp0 + (size_t)(s_) * 1024);             \
    b1##sfx = *(const v4i*)(bp1 + (size_t)(s_) * 1024);             \
} while (0)

__global__ __launch_bounds__(512, 4) void gemm_ws(const int* __restrict__ b,
                                                  const char* __restrict__ bf,
                                                  int* __restrict__ out) {
    __shared__ __align__(16) char As[64 * 1024];      // 64 KB packed b-panel
    __shared__ u32 pk[2][64 * 8];                     // 2 x 2 KB parity bits

    const int t   = threadIdx.x;
    // bijective XCD swizzle (512 % 8 == 0)
    const int bid = blockIdx.x;
    const int m0  = ((bid & 7) * 64 + (bid >> 3)) * 64;

    const int w = t >> 6, lane = t & 63, lr = lane & 31, hi = lane >> 5;
    const int axor = (lr & 7) << 4;

    // ---- stage: pack b-panel (64 x 1024 int32 -> i8) into swizzled LDS,
    // all 8 waves; b read from HBM exactly once (proven absmax=0 convention).
    {
        const int* src = b + (size_t)m0 * K_MSG;
#pragma unroll 8
        for (int i2 = 0; i2 < 32; ++i2) {
            const int i  = i2 * 2 + (t >> 8);
            const int c4 = (t & 255) * 4;
            int4 v = *(const int4*)(src + (size_t)i * K_MSG + c4);  // coalesced
            u32 p = (u32)(v.x & 1) | ((u32)(v.y & 1) << 8) |
                    ((u32)(v.z & 1) << 16) | ((u32)(v.w & 1) << 24);
            *(u32*)(As + i * 1024 + (c4 ^ ((i & 7) << 4))) = p;
        }
    }
    __syncthreads();

    if (w < 4) {
        // ================= compute waves =================
#pragma unroll 1
        for (int pass = 0; pass < 8; ++pass) {
            const char* bp0 = bf + ((size_t)pass * 8 + w * 2) * 32768 + lane * 16;
            const char* bp1 = bp0 + 32768;

            v16i acc[2][2] = {};
            v4i a0A, a1A, b0A, b1A;
            v4i a0B, a1B, b0B, b1B;

            LOADS(A, 0);
#pragma unroll 1
            for (int s = 0; s < 32; s += 2) {
                LOADS(B, s + 1);
                MFMAS(A);
                if (s + 2 < 32) LOADS(A, s + 2);
                MFMAS(B);
            }

            // ballot-pack parity into pk[pass&1]
            u32* pkc = pk[pass & 1];
#pragma unroll
            for (int mi = 0; mi < 2; ++mi) {
#pragma unroll
                for (int ni = 0; ni < 2; ++ni) {
                    const int cbL = w * 2 + ni;
#pragma unroll
                    for (int r = 0; r < 16; ++r) {
                        u64 m = __ballot((acc[mi][ni][r] & 1) != 0);
                        if ((lane & 31) == r) {
                            const int row = mi * 32 + (r & 3) + 8 * (r >> 2) + 4 * hi;
                            pkc[row * 8 + cbL] = (u32)(m >> (hi * 32));
                        }
                    }
                }
            }
            __syncthreads();
        }
        // compute waves exit; LDS stays valid until the whole block finishes
    } else {
        // ================= storer waves =================
        const int sw = w - 4;
#pragma unroll 1
        for (int pass = 0; pass < 8; ++pass) {
            if (pass > 0) {
                const u32* pkp = pk[(pass - 1) & 1];
                int* op = out + (size_t)m0 * N_CODE + (pass - 1) * 256;
#pragma unroll
                for (int rr = 0; rr < 16; ++rr) {
                    const int row = sw * 16 + rr;
                    const u32 pword = pkp[row * 8 + (lane >> 3)];
                    const int sb = (lane & 7) * 4;
                    v4i v;
                    v.x = (int)((pword >> (sb + 0)) & 1u);
                    v.y = (int)((pword >> (sb + 1)) & 1u);
                    v.z = (int)((pword >> (sb + 2)) & 1u);
                    v.w = (int)((pword >> (sb + 3)) & 1u);
                    *(v4i*)(op + (size_t)row * N_CODE + lane * 4) = v;  // 1KB/instr
                }
            }
            __syncthreads();
        }
        // tail: expand pass 7 (pk[1]); no barrier needed after the last sync
        {
            const u32* pkp = pk[1];
            int* op = out + (size_t)m0 * N_CODE + 7 * 256;
#pragma unroll
            for (int rr = 0; rr < 16; ++rr) {
                const int row = sw * 16 + rr;
                const u32 pword = pkp[row * 8 + (lane >> 3)];
                const int sb = (lane & 7) * 4;
                v4i v;
                v.x = (int)((pword >> (sb + 0)) & 1u);
                v.y = (int)((pword >> (sb + 1)) & 1u);
                v.z = (int)((pword >> (sb + 2)) & 1u);
                v.w = (int)((pword >> (sb + 3)) & 1u);
                *(v4i*)(op + (size_t)row * N_CODE + lane * 4) = v;
            }
        }
    }
}

// ---------------- fallback (only if ws too small) ---------------------------
__global__ void encode_naive(const int* __restrict__ b, const int* __restrict__ G,
                             int* __restrict__ out) {
    size_t idx = (size_t)blockIdx.x * blockDim.x + threadIdx.x;
    size_t total = (size_t)NB * N_CODE;
    if (idx >= total) return;
    int i = (int)(idx / N_CODE);
    int j = (int)(idx % N_CODE);
    int acc = 0;
    for (int k = 0; k < K_MSG; ++k)
        acc ^= b[(size_t)i * K_MSG + k] & G[(size_t)k * N_CODE + j];
    out[idx] = acc & 1;
}

extern "C" void kernel_launch(void* const* d_in, const int* in_sizes, int n_in,
                              void* d_out, int out_size, void* d_ws, size_t ws_size,
                              hipStream_t stream) {
    const int* b = (const int*)d_in[0];
    const int* G = (const int*)d_in[1];
    int* out = (int*)d_out;

    const size_t bf_bytes = (size_t)N_CODE * K_MSG;      // 2 MiB

    if (ws_size < bf_bytes) {
        size_t total = (size_t)NB * N_CODE;
        encode_naive<<<(unsigned)((total + 255) / 256), 256, 0, stream>>>(b, G, out);
        return;
    }

    char* bf = (char*)d_ws;

    pack_gBF<<<2048, 256, 0, stream>>>(G, (u32*)bf);
    gemm_ws<<<NB / 64, 512, 0, stream>>>(b, bf, out);   // 512 blocks x 8 waves
}

// Round 16
// 134.639 us; speedup vs baseline: 1.1493x; 1.1493x over previous
//
#include <hip/hip_runtime.h>
#include <stdint.h>

typedef unsigned int u32;
typedef unsigned long long u64;
typedef int v4i  __attribute__((ext_vector_type(4)));
typedef int v16i __attribute__((ext_vector_type(16)));

#define K_MSG   1024
#define N_CODE  2048
#define NB      32768

// ------------- pack G -> fragment-major i8 B (proven round 10-15) -----------
__global__ void pack_gBF(const int* __restrict__ G, u32* __restrict__ bf) {
    int idx = blockIdx.x * blockDim.x + threadIdx.x;   // 524288
    const int j  = idx & (N_CODE - 1);                 // coalesced G reads
    const int kq = idx >> 11;                          // dword of k: 0..255
    u32 p = 0;
#pragma unroll
    for (int i = 0; i < 4; ++i) {
        int v = G[(size_t)(kq * 4 + i) * N_CODE + j];
        p |= (u32)(v & 1) << (8 * i);
    }
    const int jb = j >> 5, jr = j & 31;
    const int kb = kq >> 3, hi = (kq >> 2) & 1, b4 = kq & 3;
    bf[(size_t)(jb * 32 + kb) * 256 + hi * 128 + jr * 4 + b4] = p;
}

// ---------------- all-in-one GEMM (R14 + interleaved expand) ----------------
// 512 blocks x 4 waves, 1 block per 64-row M-panel (b packed ONCE into LDS),
// 4 N-passes of 512 cols. Pass p's k-loop (wave tile 64x128, 4-deep pipeline)
// carries the EXPAND STORES of pass p-1 interleaved (2 rows per 4-step iter):
// stores issue into the k-loop's idle VMEM slots, completion never waited.
// Ballot-pack -> pk[2] double buffer; ONE barrier per pass.

#define MFMA_I8(va, vb, vc) __builtin_amdgcn_mfma_i32_32x32x32_i8(va, vb, vc, 0, 0, 0)

#define MFMA_SET(sfx) do {                              \
    acc[0][0] = MFMA_I8(a0##sfx, b0##sfx, acc[0][0]);   \
    acc[0][1] = MFMA_I8(a0##sfx, b1##sfx, acc[0][1]);   \
    acc[0][2] = MFMA_I8(a0##sfx, b2##sfx, acc[0][2]);   \
    acc[0][3] = MFMA_I8(a0##sfx, b3##sfx, acc[0][3]);   \
    acc[1][0] = MFMA_I8(a1##sfx, b0##sfx, acc[1][0]);   \
    acc[1][1] = MFMA_I8(a1##sfx, b1##sfx, acc[1][1]);   \
    acc[1][2] = MFMA_I8(a1##sfx, b2##sfx, acc[1][2]);   \
    acc[1][3] = MFMA_I8(a1##sfx, b3##sfx, acc[1][3]);   \
} while (0)

#define LOAD_SET(sfx, s_) do {                                      \
    int ao_ = lr * 1024 + ((((s_) * 32) + hi * 16) ^ axor);         \
    a0##sfx = *(const v4i*)(As + ao_);                              \
    a1##sfx = *(const v4i*)(As + ao_ + 32768);                      \
    b0##sfx = *(const v4i*)(bp0 + (size_t)(s_) * 1024);             \
    b1##sfx = *(const v4i*)(bp1 + (size_t)(s_) * 1024);             \
    b2##sfx = *(const v4i*)(bp2 + (size_t)(s_) * 1024);             \
    b3##sfx = *(const v4i*)(bp3 + (size_t)(s_) * 1024);             \
} while (0)

// expand one packed row (512 cols = 2KB) as two coalesced 1KB store instrs
#define EXPAND_ROW(pkp_, opp_, row_) do {                           \
    const u32 p0_ = (pkp_)[(row_) * 16 + (lane >> 3)];              \
    const u32 p1_ = (pkp_)[(row_) * 16 + 8 + (lane >> 3)];          \
    const int sb_ = (lane & 7) * 4;                                 \
    v4i v0_, v1_;                                                   \
    v0_.x = (int)((p0_ >> (sb_ + 0)) & 1u);                         \
    v0_.y = (int)((p0_ >> (sb_ + 1)) & 1u);                         \
    v0_.z = (int)((p0_ >> (sb_ + 2)) & 1u);                         \
    v0_.w = (int)((p0_ >> (sb_ + 3)) & 1u);                         \
    v1_.x = (int)((p1_ >> (sb_ + 0)) & 1u);                         \
    v1_.y = (int)((p1_ >> (sb_ + 1)) & 1u);                         \
    v1_.z = (int)((p1_ >> (sb_ + 2)) & 1u);                         \
    v1_.w = (int)((p1_ >> (sb_ + 3)) & 1u);                         \
    int* dst_ = (opp_) + (size_t)(row_) * N_CODE + lane * 4;        \
    *(v4i*)dst_         = v0_;                                      \
    *(v4i*)(dst_ + 256) = v1_;                                      \
} while (0)

__global__ __launch_bounds__(256, 2) void gemm_all(const int* __restrict__ b,
                                                   const char* __restrict__ bf,
                                                   int* __restrict__ out) {
    __shared__ __align__(16) char As[64 * 1024];      // 64 KB packed b-panel
    __shared__ u32 pk[2][64 * 16];                    // 2 x 4 KB parity bits

    const int t   = threadIdx.x;
    // bijective XCD swizzle (512 % 8 == 0): XCD k owns contiguous M-panels.
    const int bid = blockIdx.x;
    const int m0  = ((bid & 7) * 64 + (bid >> 3)) * 64;

    const int w = t >> 6, lane = t & 63, lr = lane & 31, hi = lane >> 5;
    const int axor = (lr & 7) << 4;

    // ---- stage: pack own b-panel (64 x 1024 int32 -> i8) into swizzled LDS
    // (proven absmax=0 in rounds 12-15). b read from HBM exactly once.
    {
        const int* src = b + (size_t)m0 * K_MSG;
#pragma unroll 8
        for (int i = 0; i < 64; ++i) {
            int4 v = *(const int4*)(src + (size_t)i * K_MSG + t * 4); // coalesced
            u32 p = (u32)(v.x & 1) | ((u32)(v.y & 1) << 8) |
                    ((u32)(v.z & 1) << 16) | ((u32)(v.w & 1) << 24);
            *(u32*)(As + i * 1024 + ((t * 4) ^ ((i & 7) << 4))) = p;
        }
    }
    __syncthreads();

#pragma unroll 1
    for (int pass = 0; pass < 4; ++pass) {
        const int cur = pass & 1;
        const u32* pkp = pk[cur ^ 1];                   // prev pass's bits
        int* opp = out + (size_t)m0 * N_CODE + (pass - 1) * 512;

        // fragment-major B bases: colblk = pass*16 + w*4 + ni, frag stride 32KB
        const char* bp0 = bf + ((size_t)pass * 16 + w * 4) * 32768 + lane * 16;
        const char* bp1 = bp0 + 32768;
        const char* bp2 = bp0 + 65536;
        const char* bp3 = bp0 + 98304;

        v16i acc[2][4] = {};
        v4i a0A, a1A, b0A, b1A, b2A, b3A;
        v4i a0B, a1B, b0B, b1B, b2B, b3B;
        v4i a0C, a1C, b0C, b1C, b2C, b3C;
        v4i a0D, a1D, b0D, b1D, b2D, b3D;

        LOAD_SET(A, 0);
        LOAD_SET(B, 1);
#pragma unroll 1
        for (int s = 0; s < 32; s += 4) {
            LOAD_SET(C, s + 2);
            LOAD_SET(D, s + 3);
            MFMA_SET(A);
            MFMA_SET(B);
            if (s + 4 < 32) {
                LOAD_SET(A, s + 4);
                LOAD_SET(B, s + 5);
            }
            MFMA_SET(C);
            MFMA_SET(D);
            // interleaved expand of pass-1: 2 rows per iter, stores issue into
            // the k-loop's idle VMEM slots; completion never waited.
            if (pass > 0) {
                const int row0 = w * 16 + (s >> 1);     // s/4*2
                EXPAND_ROW(pkp, opp, row0);
                EXPAND_ROW(pkp, opp, row0 + 1);
            }
        }

        // ---- ballot-pack parity into pk[cur] (proven R14 map):
        // low 32 = rows @hi=0, high 32 = rows @hi=1, cols = lane&31.
        u32* pkc = pk[cur];
#pragma unroll
        for (int mi = 0; mi < 2; ++mi) {
#pragma unroll
            for (int ni = 0; ni < 4; ++ni) {
                const int cbL = w * 4 + ni;
#pragma unroll
                for (int r = 0; r < 16; ++r) {
                    u64 m = __ballot((acc[mi][ni][r] & 1) != 0);
                    if ((lane & 31) == r) {
                        const int row = mi * 32 + (r & 3) + 8 * (r >> 2) + 4 * hi;
                        pkc[row * 16 + cbL] = (u32)(m >> (hi * 32));
                    }
                }
            }
        }
        __syncthreads();   // pk[cur] complete; pk[cur^1] fully consumed
    }

    // ---- tail: expand pass 3's bits (pk[1])
    {
        const u32* pkp = pk[1];
        int* opp = out + (size_t)m0 * N_CODE + 3 * 512;
#pragma unroll 4
        for (int rr = 0; rr < 16; ++rr) {
            const int row = w * 16 + rr;
            EXPAND_ROW(pkp, opp, row);
        }
    }
}

// ---------------- fallback (only if ws too small) ---------------------------
__global__ void encode_naive(const int* __restrict__ b, const int* __restrict__ G,
                             int* __restrict__ out) {
    size_t idx = (size_t)blockIdx.x * blockDim.x + threadIdx.x;
    size_t total = (size_t)NB * N_CODE;
    if (idx >= total) return;
    int i = (int)(idx / N_CODE);
    int j = (int)(idx % N_CODE);
    int acc = 0;
    for (int k = 0; k < K_MSG; ++k)
        acc ^= b[(size_t)i * K_MSG + k] & G[(size_t)k * N_CODE + j];
    out[idx] = acc & 1;
}

extern "C" void kernel_launch(void* const* d_in, const int* in_sizes, int n_in,
                              void* d_out, int out_size, void* d_ws, size_t ws_size,
                              hipStream_t stream) {
    const int* b = (const int*)d_in[0];
    const int* G = (const int*)d_in[1];
    int* out = (int*)d_out;

    const size_t bf_bytes = (size_t)N_CODE * K_MSG;      // 2 MiB

    if (ws_size < bf_bytes) {
        size_t total = (size_t)NB * N_CODE;
        encode_naive<<<(unsigned)((total + 255) / 256), 256, 0, stream>>>(b, G, out);
        return;
    }

    char* bf = (char*)d_ws;

    pack_gBF<<<2048, 256, 0, stream>>>(G, (u32*)bf);
    gemm_all<<<NB / 64, 256, 0, stream>>>(b, bf, out);   // 512 blocks
}